// Round 1
// 109.175 us; speedup vs baseline: 1.0041x; 1.0041x over previous
//
#include <hip/hip_runtime.h>

// IGANN: per-feature 2-layer MLPs (1->16->16->1), summed over 256 features + linear term.
// R23 = R22 inner loop VERBATIM + output-path restructure:
//   - NO hipMemsetAsync, NO global atomics.
//   - Each (row-block, feature-group) block writes ONE coalesced float per row into
//     d_ws[fg][32768]: subnet sums bounced through a 1 KB LDS array, folded with the
//     per-thread lin term + b3 partial, stored with a single coalesced global_store.
//   - A second tiny kernel (grid 128x256) sums the 16 partials per row (+ bias_b) from
//     L2 (2 MB, written just before -> L2-hot) into out.
//   Rationale: R22's tail issued 1.05M device-scope atomicAdds (32 per output row,
//   bursted at block-end, serialized per-line in L2) + a separate 128 KB memset
//   dispatch; the fi-loop itself is within ~2x of its VALU floor (~15 VALU/MFMA),
//   so the output path is the top remaining controllable cost.

typedef float    f32x4 __attribute__((ext_vector_type(4)));
typedef _Float16 f16x4 __attribute__((ext_vector_type(4)));
typedef __fp16   pk16x2 __attribute__((ext_vector_type(2)));

__device__ __forceinline__ f16x4 cvt4(f32x4 v) {
    pk16x2 lo = __builtin_amdgcn_cvt_pkrtz(v[0], v[1]);
    pk16x2 hi = __builtin_amdgcn_cvt_pkrtz(v[2], v[3]);
    union { unsigned u[2]; f16x4 h; } un;
    un.u[0] = __builtin_bit_cast(unsigned, lo);
    un.u[1] = __builtin_bit_cast(unsigned, hi);
    return un.h;
}

__device__ __forceinline__ f16x4 relu_h(f16x4 v) {
    f16x4 z = {};
    return __builtin_elementwise_max(v, z);
}

__device__ __forceinline__ f32x4 relu_f(f32x4 v) {
    f32x4 z = {0.f, 0.f, 0.f, 0.f};
    return __builtin_elementwise_max(v, z);
}

#define FCHUNK 16   // features per block (16 groups of 16 = 256)
#define XR     20   // x LDS row stride in f16 (banks row*10 mod 32 distinct — conflict-free)
#define W2R    20   // W2 LDS row stride in f16 (banks r*10 mod 32 distinct — conflict-free)
#define BATCH  32768

__global__ __launch_bounds__(256) void igann_kernel(
    const float* __restrict__ x,  const float* __restrict__ la,
    const float* __restrict__ bb, const float* __restrict__ W1,
    const float* __restrict__ b1, const float* __restrict__ W2,
    const float* __restrict__ b2, const float* __restrict__ W3,
    const float* __restrict__ b3, float* __restrict__ ws)
{
    const int tid = threadIdx.x;
    const int l   = tid & 63;     // lane
    const int w   = tid >> 6;     // wave in block (0..3)
    const int r   = l & 15;       // MFMA row m (A) / col n (D)
    const int g   = l >> 4;       // k-group
    const int g4  = g * 4;

    const int rb = blockIdx.x >> 4;    // row block (0..127), 256 rows each
    const int fg = blockIdx.x & 15;    // feature group (0..15)
    const int f0 = fg * FCHUNK;
    const int rowbase = rb * 256;

    __shared__ _Float16 xs [256 * XR];            // 10240 B: x slice [row][col16+pad]
    __shared__ _Float16 w2s[FCHUNK * 16 * W2R];   // 10240 B: [f][n][k16+pad]
    __shared__ _Float16 wbs[FCHUNK * 4 * 8];      //  1024 B: [f][g][w1 x4 | b1 x4]
    __shared__ float2   bws[FCHUNK * 16];         //  2048 B: [f][n] -> (b2, w3)
    __shared__ float    sums[256];                //  1024 B: per-row subnet sums
                                                  //  -> 24576 B total (6 blocks/CU)

    // ---- stage x slice (coalesced: 4 lanes cover one 64-B row-slice) ----
    {
        const int rr = tid >> 2;          // 0..63
        const int c4 = (tid & 3) * 4;     // 0,4,8,12
        #pragma unroll
        for (int it = 0; it < 4; ++it) {
            const int row = it * 64 + rr;
            f32x4 v = *(const f32x4*)(x + (size_t)(rowbase + row) * 256 + f0 + c4);
            *(f16x4*)(xs + row * XR + c4) = cvt4(v);
        }
    }
    // ---- stage W2 (thread tid owns (f,n)=(tid>>4, tid&15)) ----
    {
        const int f = tid >> 4, n = tid & 15;
        const float* src = W2 + ((size_t)(f0 + f) * 16 + n) * 16;
        _Float16* dst = w2s + (f * 16 + n) * W2R;
        #pragma unroll
        for (int q = 0; q < 4; ++q) {
            f32x4 v = *(const f32x4*)(src + q * 4);
            *(f16x4*)(dst + q * 4) = cvt4(v);
        }
    }
    // ---- stage interleaved W1|b1 (scalar f16 stores; thread tid owns (f,k)) ----
    {
        const int f = tid >> 4, k = tid & 15;
        const int base = f * 32 + (k >> 2) * 8 + (k & 3);   // [f][g][lo4|hi4]
        wbs[base]     = (_Float16)W1[(size_t)(f0 + f) * 16 + k];
        wbs[base + 4] = (_Float16)b1[(size_t)(f0 + f) * 16 + k];
    }
    // ---- stage (b2, w3) float2 pairs ----
    {
        const int f = tid >> 4, n = tid & 15;
        bws[tid] = make_float2(b2[(size_t)(f0 + f) * 16 + n],
                               W3[(size_t)(f0 + f) * 16 + n]);
    }
    __syncthreads();

    const _Float16* xw = xs + (w * 64 + r) * XR;

    f32x4 acc[4];     // [tile][j]: D row g4+j (batch row within tile), col r (channel)
    #pragma unroll
    for (int t = 0; t < 4; ++t) acc[t] = (f32x4){0.f, 0.f, 0.f, 0.f};

    for (int fi = 0; fi < FCHUNK; fi += 4) {   // rolled: keeps register pressure down
        f16x4 xv[4];
        #pragma unroll
        for (int t = 0; t < 4; ++t)
            xv[t] = *(const f16x4*)(xw + t * 16 * XR + fi);

        #pragma unroll
        for (int u = 0; u < 4; ++u) {
            const int f = fi + u;
            // adjacent f16x4 reads (8 B apart) -> ds_read2_b64
            f16x4 w1h   = *(const f16x4*)(wbs + f * 32 + g * 8);
            f16x4 b1h   = *(const f16x4*)(wbs + f * 32 + g * 8 + 4);
            f16x4 bfrag = *(const f16x4*)(w2s + (f * 16 + r) * W2R + g4);
            const float2 bw = bws[f * 16 + r];          // one ds_read_b64
            const f32x4 cinit = {bw.x, bw.x, bw.x, bw.x};   // b2 folded into MFMA C
            const f32x4 w3k4  = {bw.y, bw.y, bw.y, bw.y};

            #pragma unroll
            for (int t = 0; t < 4; ++t) {
                const _Float16 s = xv[t][u];
                f16x4 xb = {s, s, s, s};
                f16x4 h = relu_h(xb * w1h + b1h);       // v_pk_fma_f16 + v_pk_max_f16
                f32x4 d = __builtin_amdgcn_mfma_f32_16x16x16f16(h, bfrag, cinit, 0, 0, 0);
                acc[t] += relu_f(d) * w3k4;
            }
        }
    }

    // ---- channel reduce (lane bits 0..3); r==0 lanes park sums in LDS ----
    #pragma unroll
    for (int t = 0; t < 4; ++t)
        #pragma unroll
        for (int j = 0; j < 4; ++j) {
            float v = acc[t][j];
            v += __shfl_xor(v, 1, 64);
            v += __shfl_xor(v, 2, 64);
            v += __shfl_xor(v, 4, 64);
            v += __shfl_xor(v, 8, 64);
            if (r == 0)
                sums[w * 64 + t * 16 + g4 + j] = v;   // 4 lanes, stride-16B: bank-clean
        }
    __syncthreads();

    // ---- linear term + b3 partial folded in; ONE coalesced store per row ----
    float b3s = 0.f;
    #pragma unroll
    for (int c = 0; c < FCHUNK; ++c) b3s += b3[f0 + c];   // uniform -> s_loads
    float lin = 0.f;
    const _Float16* xrow = xs + tid * XR;
    #pragma unroll
    for (int c = 0; c < FCHUNK; ++c)
        lin = fmaf((float)xrow[c], la[f0 + c], lin);       // la uniform -> s_loads
    ws[(size_t)fg * BATCH + rowbase + tid] = sums[tid] + lin + b3s;
}

__global__ __launch_bounds__(256) void igann_reduce(
    const float* __restrict__ ws, const float* __restrict__ bb,
    float* __restrict__ out)
{
    const int i = blockIdx.x * 256 + threadIdx.x;
    float s = bb[0];
    #pragma unroll
    for (int gq = 0; gq < 16; ++gq)
        s += ws[(size_t)gq * BATCH + i];    // coalesced across threads; L2-hot
    out[i] = s;
}

extern "C" void kernel_launch(void* const* d_in, const int* in_sizes, int n_in,
                              void* d_out, int out_size, void* d_ws, size_t ws_size,
                              hipStream_t stream) {
    const float* x  = (const float*)d_in[0];
    const float* la = (const float*)d_in[1];
    const float* bb = (const float*)d_in[2];
    const float* W1 = (const float*)d_in[3];
    const float* b1 = (const float*)d_in[4];
    const float* W2 = (const float*)d_in[5];
    const float* b2 = (const float*)d_in[6];
    const float* W3 = (const float*)d_in[7];
    const float* b3 = (const float*)d_in[8];
    float* out = (float*)d_out;
    float* ws  = (float*)d_ws;

    dim3 grid(2048), block(256);   // 128 row-blocks x 16 feature-groups
    hipLaunchKernelGGL(igann_kernel, grid, block, 0, stream,
                       x, la, bb, W1, b1, W2, b2, W3, b3, ws);
    hipLaunchKernelGGL(igann_reduce, dim3(128), block, 0, stream,
                       ws, bb, out);
}

// Round 2
// 106.613 us; speedup vs baseline: 1.0283x; 1.0240x over previous
//
#include <hip/hip_runtime.h>

// IGANN: per-feature 2-layer MLPs (1->16->16->1), summed over 256 features + linear term.
// R24 = R23 + occupancy push (layout-only, numerics identical):
//   - xs: swizzled [256][16] f16 (8 KB, was 10 KB padded XR=20). Granule-XOR by
//     (row>>2)&3 keeps the 16-row b64 fragment read conflict-free (<=2 lanes/bank
//     per phase = free per m136) while dropping the pad.
//   - w2s: swizzled [16][16][16] f16 (8 KB, was 10 KB W2R=20). Granule-XOR by
//     (n>>2)&3 breaks the n/n+4/n+8/n+12 same-bank collision that plagued W2R=16.
//   - sums overlaid on wbs (dead after the fi-loop; extra __syncthreads guards the
//     alias). bws stays float2 (no f16 precision risk on b2/w3).
//   - LDS 24576 -> 19456 B and __launch_bounds__(256,8): 8 blocks/CU, 32 waves/CU,
//     grid 2048 = exactly one residency round (no tail), VGPR capped at 64
//     (in-loop live set ~55-60 by hand count -> graceful, not spilling).
//   Rationale: R23's atomic/memset removal was neutral -> output path never mattered;
//   kernel floors (VALU ~6us, MFMA ~1us, LDS ~1.3us) are far below its measured
//   range -> latency/occupancy-bound. This attacks occupancy + scheduling tail.

typedef float    f32x4 __attribute__((ext_vector_type(4)));
typedef _Float16 f16x4 __attribute__((ext_vector_type(4)));
typedef __fp16   pk16x2 __attribute__((ext_vector_type(2)));

__device__ __forceinline__ f16x4 cvt4(f32x4 v) {
    pk16x2 lo = __builtin_amdgcn_cvt_pkrtz(v[0], v[1]);
    pk16x2 hi = __builtin_amdgcn_cvt_pkrtz(v[2], v[3]);
    union { unsigned u[2]; f16x4 h; } un;
    un.u[0] = __builtin_bit_cast(unsigned, lo);
    un.u[1] = __builtin_bit_cast(unsigned, hi);
    return un.h;
}

__device__ __forceinline__ f16x4 relu_h(f16x4 v) {
    f16x4 z = {};
    return __builtin_elementwise_max(v, z);
}

__device__ __forceinline__ f32x4 relu_f(f32x4 v) {
    f32x4 z = {0.f, 0.f, 0.f, 0.f};
    return __builtin_elementwise_max(v, z);
}

#define FCHUNK 16   // features per block (16 groups of 16 = 256)
#define BATCH  32768

__global__ __launch_bounds__(256, 8) void igann_kernel(
    const float* __restrict__ x,  const float* __restrict__ la,
    const float* __restrict__ bb, const float* __restrict__ W1,
    const float* __restrict__ b1, const float* __restrict__ W2,
    const float* __restrict__ b2, const float* __restrict__ W3,
    const float* __restrict__ b3, float* __restrict__ ws)
{
    const int tid = threadIdx.x;
    const int l   = tid & 63;     // lane
    const int w   = tid >> 6;     // wave in block (0..3)
    const int r   = l & 15;       // MFMA row m (A) / col n (D)
    const int g   = l >> 4;       // k-group
    const int g4  = g * 4;

    const int rb = blockIdx.x >> 4;    // row block (0..127), 256 rows each
    const int fg = blockIdx.x & 15;    // feature group (0..15)
    const int f0 = fg * FCHUNK;
    const int rowbase = rb * 256;

    // xs  [row][granule^((row>>2)&3)][4]  : 8192 B, conflict-free b64 frag reads
    // w2s [f][n][granule^((n>>2)&3)][4]   : 8192 B, conflict-free bfrag reads
    // wbs [f][g][w1 x4 | b1 x4] f16       : 1024 B, dead after loop -> sums overlay
    // bws [f][n] -> (b2, w3) float2       : 2048 B
    __shared__ _Float16 xs [256 * 16];
    __shared__ _Float16 w2s[FCHUNK * 16 * 16];
    __shared__ float    wbs_sums[256];          // union: wbs (f16 view) / sums (f32)
    __shared__ float2   bws[FCHUNK * 16];
    _Float16* wbs = (_Float16*)wbs_sums;
    float*    sums = wbs_sums;                  // -> 19456 B total: 8 blocks/CU

    // ---- stage x slice (coalesced: 4 lanes cover one 64-B row-slice) ----
    {
        const int rr  = tid >> 2;         // 0..63
        const int c4g = tid & 3;          // granule 0..3
        const int sw  = (rr >> 2) & 3;    // (row>>2)&3 — it*64 doesn't touch bits 2..3
        #pragma unroll
        for (int it = 0; it < 4; ++it) {
            const int row = it * 64 + rr;
            f32x4 v = *(const f32x4*)(x + (size_t)(rowbase + row) * 256 + f0 + c4g * 4);
            *(f16x4*)(xs + row * 16 + ((c4g ^ sw) & 3) * 4) = cvt4(v);
        }
    }
    // ---- stage W2 (thread tid owns (f,n)=(tid>>4, tid&15)) ----
    {
        const int f = tid >> 4, n = tid & 15;
        const int sw = (n >> 2) & 3;
        const float* src = W2 + ((size_t)(f0 + f) * 16 + n) * 16;
        _Float16* dst = w2s + (f * 16 + n) * 16;
        #pragma unroll
        for (int q = 0; q < 4; ++q) {
            f32x4 v = *(const f32x4*)(src + q * 4);
            *(f16x4*)(dst + ((q ^ sw) & 3) * 4) = cvt4(v);
        }
    }
    // ---- stage interleaved W1|b1 (scalar f16 stores; thread tid owns (f,k)) ----
    {
        const int f = tid >> 4, k = tid & 15;
        const int base = f * 32 + (k >> 2) * 8 + (k & 3);   // [f][g][lo4|hi4]
        wbs[base]     = (_Float16)W1[(size_t)(f0 + f) * 16 + k];
        wbs[base + 4] = (_Float16)b1[(size_t)(f0 + f) * 16 + k];
    }
    // ---- stage (b2, w3) float2 pairs ----
    {
        const int f = tid >> 4, n = tid & 15;
        bws[tid] = make_float2(b2[(size_t)(f0 + f) * 16 + n],
                               W3[(size_t)(f0 + f) * 16 + n]);
    }
    __syncthreads();

    const _Float16* xw  = xs + (w * 64 + r) * 16;
    const int       xsw = ((w * 64 + r) >> 2) & 3;          // per-lane swizzle sel
    const _Float16* w2p = w2s + r * 16 + ((g ^ ((r >> 2) & 3)) & 3) * 4;

    f32x4 acc[4];     // [tile][j]: D row g4+j (batch row within tile), col r (channel)
    #pragma unroll
    for (int t = 0; t < 4; ++t) acc[t] = (f32x4){0.f, 0.f, 0.f, 0.f};

    for (int fi = 0; fi < FCHUNK; fi += 4) {   // rolled: keeps register pressure down
        const int xoff = (((fi >> 2) ^ xsw) & 3) * 4;
        f16x4 xv[4];
        #pragma unroll
        for (int t = 0; t < 4; ++t)
            xv[t] = *(const f16x4*)(xw + t * 256 + xoff);    // t*16 rows * 16 f16

        #pragma unroll
        for (int u = 0; u < 4; ++u) {
            const int f = fi + u;
            // adjacent f16x4 reads (8 B apart) -> ds_read2_b64
            f16x4 w1h   = *(const f16x4*)(wbs + f * 32 + g * 8);
            f16x4 b1h   = *(const f16x4*)(wbs + f * 32 + g * 8 + 4);
            f16x4 bfrag = *(const f16x4*)(w2p + f * 256);
            const float2 bw = bws[f * 16 + r];          // one ds_read_b64
            const f32x4 cinit = {bw.x, bw.x, bw.x, bw.x};   // b2 folded into MFMA C
            const f32x4 w3k4  = {bw.y, bw.y, bw.y, bw.y};

            #pragma unroll
            for (int t = 0; t < 4; ++t) {
                const _Float16 s = xv[t][u];
                f16x4 xb = {s, s, s, s};
                f16x4 h = relu_h(xb * w1h + b1h);       // v_pk_fma_f16 + v_pk_max_f16
                f32x4 d = __builtin_amdgcn_mfma_f32_16x16x16f16(h, bfrag, cinit, 0, 0, 0);
                acc[t] = __builtin_elementwise_fma(relu_f(d), w3k4, acc[t]);
            }
        }
    }

    __syncthreads();   // all waves done reading wbs before sums overlays it

    // ---- channel reduce (lane bits 0..3); r==0 lanes park sums in LDS ----
    #pragma unroll
    for (int t = 0; t < 4; ++t)
        #pragma unroll
        for (int j = 0; j < 4; ++j) {
            float v = acc[t][j];
            v += __shfl_xor(v, 1, 64);
            v += __shfl_xor(v, 2, 64);
            v += __shfl_xor(v, 4, 64);
            v += __shfl_xor(v, 8, 64);
            if (r == 0)
                sums[w * 64 + t * 16 + g4 + j] = v;   // 4 lanes, stride-16B: bank-clean
        }
    __syncthreads();

    // ---- linear term + b3 partial folded in; ONE coalesced store per row ----
    float b3s = 0.f;
    #pragma unroll
    for (int c = 0; c < FCHUNK; ++c) b3s += b3[f0 + c];   // uniform -> s_loads
    float lin = 0.f;
    {
        const int swe = (tid >> 2) & 3;
        #pragma unroll
        for (int gq = 0; gq < 4; ++gq) {
            f16x4 xv4 = *(const f16x4*)(xs + tid * 16 + ((gq ^ swe) & 3) * 4);
            #pragma unroll
            for (int e = 0; e < 4; ++e)
                lin = fmaf((float)xv4[e], la[f0 + gq * 4 + e], lin);  // la uniform
        }
    }
    ws[(size_t)fg * BATCH + rowbase + tid] = sums[tid] + lin + b3s;
}

__global__ __launch_bounds__(256) void igann_reduce(
    const float* __restrict__ ws, const float* __restrict__ bb,
    float* __restrict__ out)
{
    const int i = blockIdx.x * 256 + threadIdx.x;
    float s = bb[0];
    #pragma unroll
    for (int gq = 0; gq < 16; ++gq)
        s += ws[(size_t)gq * BATCH + i];    // coalesced across threads; L2-hot
    out[i] = s;
}

extern "C" void kernel_launch(void* const* d_in, const int* in_sizes, int n_in,
                              void* d_out, int out_size, void* d_ws, size_t ws_size,
                              hipStream_t stream) {
    const float* x  = (const float*)d_in[0];
    const float* la = (const float*)d_in[1];
    const float* bb = (const float*)d_in[2];
    const float* W1 = (const float*)d_in[3];
    const float* b1 = (const float*)d_in[4];
    const float* W2 = (const float*)d_in[5];
    const float* b2 = (const float*)d_in[6];
    const float* W3 = (const float*)d_in[7];
    const float* b3 = (const float*)d_in[8];
    float* out = (float*)d_out;
    float* ws  = (float*)d_ws;

    dim3 grid(2048), block(256);   // 128 row-blocks x 16 feature-groups
    hipLaunchKernelGGL(igann_kernel, grid, block, 0, stream,
                       x, la, bb, W1, b1, W2, b2, W3, b3, ws);
    hipLaunchKernelGGL(igann_reduce, dim3(128), block, 0, stream,
                       ws, bb, out);
}

// Round 3
// 105.763 us; speedup vs baseline: 1.0365x; 1.0080x over previous
//
#include <hip/hip_runtime.h>

// IGANN: per-feature 2-layer MLPs (1->16->16->1), summed over 256 features + linear term.
// R25 = R24 + XCD-pinning block swizzle (layout-only, numerics identical):
//   - Dispatch_Id arithmetic (fills 13 apart) shows: 1 poison fill (43us, harness-fixed)
//     + igann + reduce + ~10 restores per iteration. igann is the remaining target.
//   - Default round-robin bid->XCD spreads an rb's 16 fg-blocks across all 8 XCDs;
//     adjacent fgs share a 128-B L2 line -> every x line fetched ~2x from HBM
//     (67 MB vs 33.5) and the stage burst each block sees is ~2x longer.
//   - Swizzle: rb = (bid&7) + 8*((bid>>3)&15), fg = bid>>7. Bijective; rb%8 == bid%8
//     -> all 16 fgs of an rb land on ONE XCD (round-robin assumption, perf-only);
//     exactly 256 blocks/XCD. Shared x lines become 1 HBM fetch + 15 L2 hits.
//   - reduce: 256 blocks x 128 threads (was 128x256) -> full-CU coverage.

typedef float    f32x4 __attribute__((ext_vector_type(4)));
typedef _Float16 f16x4 __attribute__((ext_vector_type(4)));
typedef __fp16   pk16x2 __attribute__((ext_vector_type(2)));

__device__ __forceinline__ f16x4 cvt4(f32x4 v) {
    pk16x2 lo = __builtin_amdgcn_cvt_pkrtz(v[0], v[1]);
    pk16x2 hi = __builtin_amdgcn_cvt_pkrtz(v[2], v[3]);
    union { unsigned u[2]; f16x4 h; } un;
    un.u[0] = __builtin_bit_cast(unsigned, lo);
    un.u[1] = __builtin_bit_cast(unsigned, hi);
    return un.h;
}

__device__ __forceinline__ f16x4 relu_h(f16x4 v) {
    f16x4 z = {};
    return __builtin_elementwise_max(v, z);
}

__device__ __forceinline__ f32x4 relu_f(f32x4 v) {
    f32x4 z = {0.f, 0.f, 0.f, 0.f};
    return __builtin_elementwise_max(v, z);
}

#define FCHUNK 16   // features per block (16 groups of 16 = 256)
#define BATCH  32768

__global__ __launch_bounds__(256, 8) void igann_kernel(
    const float* __restrict__ x,  const float* __restrict__ la,
    const float* __restrict__ bb, const float* __restrict__ W1,
    const float* __restrict__ b1, const float* __restrict__ W2,
    const float* __restrict__ b2, const float* __restrict__ W3,
    const float* __restrict__ b3, float* __restrict__ ws)
{
    const int tid = threadIdx.x;
    const int l   = tid & 63;     // lane
    const int w   = tid >> 6;     // wave in block (0..3)
    const int r   = l & 15;       // MFMA row m (A) / col n (D)
    const int g   = l >> 4;       // k-group
    const int g4  = g * 4;

    // XCD-pinning swizzle: all 16 fg-blocks of an rb satisfy bid%8 == rb%8
    // -> same XCD under round-robin assignment; shared x lines hit in that L2.
    const int bid = blockIdx.x;
    const int rb  = (bid & 7) + (((bid >> 3) & 15) << 3);   // 0..127
    const int fg  = bid >> 7;                               // 0..15
    const int f0  = fg * FCHUNK;
    const int rowbase = rb * 256;

    // xs  [row][granule^((row>>2)&3)][4]  : 8192 B, conflict-free b64 frag reads
    // w2s [f][n][granule^((n>>2)&3)][4]   : 8192 B, conflict-free bfrag reads
    // wbs [f][g][w1 x4 | b1 x4] f16       : 1024 B, dead after loop -> sums overlay
    // bws [f][n] -> (b2, w3) float2       : 2048 B
    __shared__ _Float16 xs [256 * 16];
    __shared__ _Float16 w2s[FCHUNK * 16 * 16];
    __shared__ float    wbs_sums[256];          // union: wbs (f16 view) / sums (f32)
    __shared__ float2   bws[FCHUNK * 16];
    _Float16* wbs = (_Float16*)wbs_sums;
    float*    sums = wbs_sums;                  // -> 19456 B total: 8 blocks/CU

    // ---- stage x slice (coalesced: 4 lanes cover one 64-B row-slice) ----
    {
        const int rr  = tid >> 2;         // 0..63
        const int c4g = tid & 3;          // granule 0..3
        const int sw  = (rr >> 2) & 3;    // (row>>2)&3 — it*64 doesn't touch bits 2..3
        #pragma unroll
        for (int it = 0; it < 4; ++it) {
            const int row = it * 64 + rr;
            f32x4 v = *(const f32x4*)(x + (size_t)(rowbase + row) * 256 + f0 + c4g * 4);
            *(f16x4*)(xs + row * 16 + ((c4g ^ sw) & 3) * 4) = cvt4(v);
        }
    }
    // ---- stage W2 (thread tid owns (f,n)=(tid>>4, tid&15)) ----
    {
        const int f = tid >> 4, n = tid & 15;
        const int sw = (n >> 2) & 3;
        const float* src = W2 + ((size_t)(f0 + f) * 16 + n) * 16;
        _Float16* dst = w2s + (f * 16 + n) * 16;
        #pragma unroll
        for (int q = 0; q < 4; ++q) {
            f32x4 v = *(const f32x4*)(src + q * 4);
            *(f16x4*)(dst + ((q ^ sw) & 3) * 4) = cvt4(v);
        }
    }
    // ---- stage interleaved W1|b1 (scalar f16 stores; thread tid owns (f,k)) ----
    {
        const int f = tid >> 4, k = tid & 15;
        const int base = f * 32 + (k >> 2) * 8 + (k & 3);   // [f][g][lo4|hi4]
        wbs[base]     = (_Float16)W1[(size_t)(f0 + f) * 16 + k];
        wbs[base + 4] = (_Float16)b1[(size_t)(f0 + f) * 16 + k];
    }
    // ---- stage (b2, w3) float2 pairs ----
    {
        const int f = tid >> 4, n = tid & 15;
        bws[tid] = make_float2(b2[(size_t)(f0 + f) * 16 + n],
                               W3[(size_t)(f0 + f) * 16 + n]);
    }
    __syncthreads();

    const _Float16* xw  = xs + (w * 64 + r) * 16;
    const int       xsw = ((w * 64 + r) >> 2) & 3;          // per-lane swizzle sel
    const _Float16* w2p = w2s + r * 16 + ((g ^ ((r >> 2) & 3)) & 3) * 4;

    f32x4 acc[4];     // [tile][j]: D row g4+j (batch row within tile), col r (channel)
    #pragma unroll
    for (int t = 0; t < 4; ++t) acc[t] = (f32x4){0.f, 0.f, 0.f, 0.f};

    for (int fi = 0; fi < FCHUNK; fi += 4) {   // rolled: keeps register pressure down
        const int xoff = (((fi >> 2) ^ xsw) & 3) * 4;
        f16x4 xv[4];
        #pragma unroll
        for (int t = 0; t < 4; ++t)
            xv[t] = *(const f16x4*)(xw + t * 256 + xoff);    // t*16 rows * 16 f16

        #pragma unroll
        for (int u = 0; u < 4; ++u) {
            const int f = fi + u;
            // adjacent f16x4 reads (8 B apart) -> ds_read2_b64
            f16x4 w1h   = *(const f16x4*)(wbs + f * 32 + g * 8);
            f16x4 b1h   = *(const f16x4*)(wbs + f * 32 + g * 8 + 4);
            f16x4 bfrag = *(const f16x4*)(w2p + f * 256);
            const float2 bw = bws[f * 16 + r];          // one ds_read_b64
            const f32x4 cinit = {bw.x, bw.x, bw.x, bw.x};   // b2 folded into MFMA C
            const f32x4 w3k4  = {bw.y, bw.y, bw.y, bw.y};

            #pragma unroll
            for (int t = 0; t < 4; ++t) {
                const _Float16 s = xv[t][u];
                f16x4 xb = {s, s, s, s};
                f16x4 h = relu_h(xb * w1h + b1h);       // v_pk_fma_f16 + v_pk_max_f16
                f32x4 d = __builtin_amdgcn_mfma_f32_16x16x16f16(h, bfrag, cinit, 0, 0, 0);
                acc[t] = __builtin_elementwise_fma(relu_f(d), w3k4, acc[t]);
            }
        }
    }

    __syncthreads();   // all waves done reading wbs before sums overlays it

    // ---- channel reduce (lane bits 0..3); r==0 lanes park sums in LDS ----
    #pragma unroll
    for (int t = 0; t < 4; ++t)
        #pragma unroll
        for (int j = 0; j < 4; ++j) {
            float v = acc[t][j];
            v += __shfl_xor(v, 1, 64);
            v += __shfl_xor(v, 2, 64);
            v += __shfl_xor(v, 4, 64);
            v += __shfl_xor(v, 8, 64);
            if (r == 0)
                sums[w * 64 + t * 16 + g4 + j] = v;   // 4 lanes, stride-16B: bank-clean
        }
    __syncthreads();

    // ---- linear term + b3 partial folded in; ONE coalesced store per row ----
    float b3s = 0.f;
    #pragma unroll
    for (int c = 0; c < FCHUNK; ++c) b3s += b3[f0 + c];   // uniform -> s_loads
    float lin = 0.f;
    {
        const int swe = (tid >> 2) & 3;
        #pragma unroll
        for (int gq = 0; gq < 4; ++gq) {
            f16x4 xv4 = *(const f16x4*)(xs + tid * 16 + ((gq ^ swe) & 3) * 4);
            #pragma unroll
            for (int e = 0; e < 4; ++e)
                lin = fmaf((float)xv4[e], la[f0 + gq * 4 + e], lin);  // la uniform
        }
    }
    ws[(size_t)fg * BATCH + rowbase + tid] = sums[tid] + lin + b3s;
}

__global__ __launch_bounds__(128) void igann_reduce(
    const float* __restrict__ ws, const float* __restrict__ bb,
    float* __restrict__ out)
{
    const int i = blockIdx.x * 128 + threadIdx.x;
    float s = bb[0];
    #pragma unroll
    for (int gq = 0; gq < 16; ++gq)
        s += ws[(size_t)gq * BATCH + i];    // coalesced across threads; L2-hot
    out[i] = s;
}

extern "C" void kernel_launch(void* const* d_in, const int* in_sizes, int n_in,
                              void* d_out, int out_size, void* d_ws, size_t ws_size,
                              hipStream_t stream) {
    const float* x  = (const float*)d_in[0];
    const float* la = (const float*)d_in[1];
    const float* bb = (const float*)d_in[2];
    const float* W1 = (const float*)d_in[3];
    const float* b1 = (const float*)d_in[4];
    const float* W2 = (const float*)d_in[5];
    const float* b2 = (const float*)d_in[6];
    const float* W3 = (const float*)d_in[7];
    const float* b3 = (const float*)d_in[8];
    float* out = (float*)d_out;
    float* ws  = (float*)d_ws;

    dim3 grid(2048), block(256);   // 2048 = 8 XCD groups x 16 rb x 16 fg (swizzled)
    hipLaunchKernelGGL(igann_kernel, grid, block, 0, stream,
                       x, la, bb, W1, b1, W2, b2, W3, b3, ws);
    hipLaunchKernelGGL(igann_reduce, dim3(256), dim3(128), 0, stream,
                       ws, bb, out);
}